// Round 1
// baseline (4280.837 us; speedup 1.0000x reference)
//
#include <hip/hip_runtime.h>

#define N_NODES 100000
#define N_EDGES 1600000

// ---------------------------------------------------------------------------
// GEMM1: support1[N,128] = x[N,128] @ W1[128,128]   (bias deferred to after agg)
// W1 (64 KB) cached in LDS; 8 rows per block-iteration; float4 throughout.
// ---------------------------------------------------------------------------
__global__ __launch_bounds__(256) void gemm_x_w1(const float* __restrict__ x,
                                                 const float* __restrict__ W,
                                                 float* __restrict__ out, int N) {
    __shared__ float4 Ws[128 * 32];  // 128 rows x 128 cols as float4 (64 KB)
    for (int i = threadIdx.x; i < 128 * 32; i += 256)
        Ws[i] = ((const float4*)W)[i];
    __syncthreads();

    const int r  = threadIdx.x >> 5;   // 0..7  (row within group)
    const int c4 = threadIdx.x & 31;   // 0..31 (float4 column)

    for (int row0 = blockIdx.x * 8; row0 < N; row0 += gridDim.x * 8) {
        const int row = row0 + r;
        if (row < N) {
            const float4* xr = (const float4*)(x + (size_t)row * 128);
            float4 acc = make_float4(0.f, 0.f, 0.f, 0.f);
#pragma unroll 4
            for (int k4 = 0; k4 < 32; ++k4) {
                float4 xv = xr[k4];
                float4 w0 = Ws[(4 * k4 + 0) * 32 + c4];
                float4 w1 = Ws[(4 * k4 + 1) * 32 + c4];
                float4 w2 = Ws[(4 * k4 + 2) * 32 + c4];
                float4 w3 = Ws[(4 * k4 + 3) * 32 + c4];
                acc.x += xv.x * w0.x + xv.y * w1.x + xv.z * w2.x + xv.w * w3.x;
                acc.y += xv.x * w0.y + xv.y * w1.y + xv.z * w2.y + xv.w * w3.y;
                acc.z += xv.x * w0.z + xv.y * w1.z + xv.z * w2.z + xv.w * w3.z;
                acc.w += xv.x * w0.w + xv.y * w1.w + xv.z * w2.w + xv.w * w3.w;
            }
            ((float4*)(out + (size_t)row * 128))[c4] = acc;
        }
    }
}

// ---------------------------------------------------------------------------
// GEMM2 (fused bias1 + ReLU): support2[N,64] = relu(agg1 + b1) @ W2[128,64]
// W2 (32 KB) + b1 in LDS; 16 rows per block-iteration.
// ---------------------------------------------------------------------------
__global__ __launch_bounds__(256) void gemm_h_w2(const float* __restrict__ agg,
                                                 const float* __restrict__ b1,
                                                 const float* __restrict__ W,
                                                 float* __restrict__ out, int N) {
    __shared__ float4 Ws[128 * 16];  // 128 rows x 64 cols as float4 (32 KB)
    __shared__ float4 b1s[32];
    for (int i = threadIdx.x; i < 128 * 16; i += 256)
        Ws[i] = ((const float4*)W)[i];
    if (threadIdx.x < 32) b1s[threadIdx.x] = ((const float4*)b1)[threadIdx.x];
    __syncthreads();

    const int r  = threadIdx.x >> 4;   // 0..15
    const int c4 = threadIdx.x & 15;   // 0..15 (float4 column of 64)

    for (int row0 = blockIdx.x * 16; row0 < N; row0 += gridDim.x * 16) {
        const int row = row0 + r;
        if (row < N) {
            const float4* ar = (const float4*)(agg + (size_t)row * 128);
            float4 acc = make_float4(0.f, 0.f, 0.f, 0.f);
#pragma unroll 4
            for (int k4 = 0; k4 < 32; ++k4) {
                float4 av = ar[k4];
                float4 bv = b1s[k4];
                float hx = fmaxf(av.x + bv.x, 0.f);
                float hy = fmaxf(av.y + bv.y, 0.f);
                float hz = fmaxf(av.z + bv.z, 0.f);
                float hw = fmaxf(av.w + bv.w, 0.f);
                float4 w0 = Ws[(4 * k4 + 0) * 16 + c4];
                float4 w1 = Ws[(4 * k4 + 1) * 16 + c4];
                float4 w2 = Ws[(4 * k4 + 2) * 16 + c4];
                float4 w3 = Ws[(4 * k4 + 3) * 16 + c4];
                acc.x += hx * w0.x + hy * w1.x + hz * w2.x + hw * w3.x;
                acc.y += hx * w0.y + hy * w1.y + hz * w2.y + hw * w3.y;
                acc.z += hx * w0.z + hy * w1.z + hz * w2.z + hw * w3.z;
                acc.w += hx * w0.w + hy * w1.w + hz * w2.w + hw * w3.w;
            }
            ((float4*)(out + (size_t)row * 64))[c4] = acc;
        }
    }
}

// ---------------------------------------------------------------------------
// Edge scatter: agg[dst] += ew * sup[src], FEAT = 4<<LOGC floats per row.
// One thread per (edge, float4-chunk): float4 gather + 4 fp32 atomics.
// ---------------------------------------------------------------------------
template <int LOGC>
__global__ __launch_bounds__(256) void scatter_edges(const float* __restrict__ sup,
                                                     const int* __restrict__ dst,
                                                     const int* __restrict__ src,
                                                     const float* __restrict__ ew,
                                                     float* __restrict__ agg) {
    constexpr int C    = 1 << LOGC;   // float4 chunks per row
    constexpr int FEAT = C * 4;
    const int tid = blockIdx.x * 256 + threadIdx.x;
    const int e   = tid >> LOGC;
    const int c   = tid & (C - 1);
    if (e >= N_EDGES) return;

    const int   s = src[e];
    const int   d = dst[e];
    const float w = ew[e];

    float4 v = ((const float4*)(sup + (size_t)s * FEAT))[c];
    float* p = agg + (size_t)d * FEAT + c * 4;
    atomicAdd(p + 0, w * v.x);
    atomicAdd(p + 1, w * v.y);
    atomicAdd(p + 2, w * v.z);
    atomicAdd(p + 3, w * v.w);
}

// ---------------------------------------------------------------------------
// Initialize output rows to b2 (scatter2 then accumulates on top).
// ---------------------------------------------------------------------------
__global__ __launch_bounds__(256) void init_out_b2(float* __restrict__ out,
                                                   const float* __restrict__ b2) {
    const int tid = blockIdx.x * 256 + threadIdx.x;  // over N_NODES*16 float4
    if (tid >= N_NODES * 16) return;
    const int c4 = tid & 15;
    ((float4*)out)[tid] = ((const float4*)b2)[c4];
}

extern "C" void kernel_launch(void* const* d_in, const int* in_sizes, int n_in,
                              void* d_out, int out_size, void* d_ws, size_t ws_size,
                              hipStream_t stream) {
    const float* x  = (const float*)d_in[0];
    const int*   ei = (const int*)d_in[1];   // [2, E]: row 0 = dst, row 1 = src
    const float* ew = (const float*)d_in[2];
    const float* W1 = (const float*)d_in[3];
    const float* b1 = (const float*)d_in[4];
    const float* W2 = (const float*)d_in[5];
    const float* b2 = (const float*)d_in[6];
    float* out = (float*)d_out;

    // Workspace layout: sup [N*128 f32] (reused as support2 [N*64]), agg1 [N*128 f32]
    float* sup  = (float*)d_ws;
    float* agg1 = sup + (size_t)N_NODES * 128;

    const int* dstIdx = ei;
    const int* srcIdx = ei + N_EDGES;

    // Layer 1
    hipMemsetAsync(agg1, 0, (size_t)N_NODES * 128 * sizeof(float), stream);
    gemm_x_w1<<<1024, 256, 0, stream>>>(x, W1, sup, N_NODES);
    scatter_edges<5><<<(N_EDGES * 32) / 256, 256, 0, stream>>>(sup, dstIdx, srcIdx, ew, agg1);

    // Layer 2 (bias1 + ReLU fused into GEMM2 load)
    gemm_h_w2<<<1024, 256, 0, stream>>>(agg1, b1, W2, sup, N_NODES);
    init_out_b2<<<(N_NODES * 16 + 255) / 256, 256, 0, stream>>>(out, b2);
    scatter_edges<4><<<(N_EDGES * 16) / 256, 256, 0, stream>>>(sup, dstIdx, srcIdx, ew, out);
}

// Round 2
// 844.354 us; speedup vs baseline: 5.0700x; 5.0700x over previous
//
#include <hip/hip_runtime.h>

#define N_NODES 100000
#define N_EDGES 1600000

// ===========================================================================
// CSR build (counting sort by dst): deg histogram -> exclusive scan -> fill.
// Replaces 307M fp32 atomics with 3.2M int atomics.
// ===========================================================================
__global__ __launch_bounds__(256) void count_deg(const int* __restrict__ dst,
                                                 int* __restrict__ deg) {
    const int e = blockIdx.x * 256 + threadIdx.x;
    if (e < N_EDGES) atomicAdd(&deg[dst[e]], 1);
}

// Single-block exclusive scan of deg[0..N) -> offs[0..N], cursor copy.
__global__ __launch_bounds__(1024) void scan_deg(const int* __restrict__ deg,
                                                 int* __restrict__ offs,
                                                 int* __restrict__ cursor) {
    __shared__ int sums[1024];
    const int t = threadIdx.x;
    const int CHUNK = (N_NODES + 1023) / 1024;  // 98; 98*1024 >= N
    const int beg = t * CHUNK;
    const int end = min(beg + CHUNK, N_NODES);
    int s = 0;
    for (int i = beg; i < end; ++i) s += deg[i];
    sums[t] = s;
    __syncthreads();
    // Hillis-Steele inclusive scan over 1024 partials
    for (int off = 1; off < 1024; off <<= 1) {
        int v = (t >= off) ? sums[t - off] : 0;
        __syncthreads();
        sums[t] += v;
        __syncthreads();
    }
    int run = (t == 0) ? 0 : sums[t - 1];
    for (int i = beg; i < end; ++i) {
        offs[i] = run;
        cursor[i] = run;
        run += deg[i];
    }
    if (t == 0) offs[N_NODES] = sums[1023];
}

__global__ __launch_bounds__(256) void fill_csr(const int* __restrict__ dst,
                                                const int* __restrict__ src,
                                                const float* __restrict__ ew,
                                                int* __restrict__ cursor,
                                                int* __restrict__ csr_src,
                                                float* __restrict__ csr_w) {
    const int e = blockIdx.x * 256 + threadIdx.x;
    if (e >= N_EDGES) return;
    const int p = atomicAdd(&cursor[dst[e]], 1);
    csr_src[p] = src[e];
    csr_w[p]   = ew[e];
}

// ===========================================================================
// Gather-aggregate: one wave64 per node. out[n] = bias + sum_j w_j*feat[src_j].
// FEAT=128: float2/lane; FEAT=64: 1 float/lane. 2-edge unroll for MLP.
// ===========================================================================
template <int FEAT>
__global__ __launch_bounds__(256) void aggregate(const float* __restrict__ feat,
                                                 const int* __restrict__ offs,
                                                 const int* __restrict__ csr_src,
                                                 const float* __restrict__ csr_w,
                                                 const float* __restrict__ bias,
                                                 float* __restrict__ out) {
    const int n    = (blockIdx.x * 256 + threadIdx.x) >> 6;  // wave id = node
    const int lane = threadIdx.x & 63;
    if (n >= N_NODES) return;
    const int beg = offs[n], end = offs[n + 1];

    if constexpr (FEAT == 128) {
        float2 acc = make_float2(0.f, 0.f);
        int j = beg;
        for (; j + 1 < end; j += 2) {
            const int   s0 = csr_src[j],   s1 = csr_src[j + 1];
            const float w0 = csr_w[j],     w1 = csr_w[j + 1];
            const float2 v0 = ((const float2*)(feat + (size_t)s0 * 128))[lane];
            const float2 v1 = ((const float2*)(feat + (size_t)s1 * 128))[lane];
            acc.x += w0 * v0.x + w1 * v1.x;
            acc.y += w0 * v0.y + w1 * v1.y;
        }
        if (j < end) {
            const float2 v = ((const float2*)(feat + (size_t)csr_src[j] * 128))[lane];
            acc.x += csr_w[j] * v.x;
            acc.y += csr_w[j] * v.y;
        }
        ((float2*)(out + (size_t)n * 128))[lane] = acc;
    } else {
        float acc = bias[lane];
        int j = beg;
        for (; j + 1 < end; j += 2) {
            const int   s0 = csr_src[j], s1 = csr_src[j + 1];
            const float w0 = csr_w[j],   w1 = csr_w[j + 1];
            acc += w0 * feat[(size_t)s0 * 64 + lane] + w1 * feat[(size_t)s1 * 64 + lane];
        }
        if (j < end) acc += csr_w[j] * feat[(size_t)csr_src[j] * 64 + lane];
        out[(size_t)n * 64 + lane] = acc;
    }
}

// ===========================================================================
// Fused double GEMM: sup2[N,64] = relu(aggP[N,128] @ W1 + b1) @ W2.
// W1 (64KB) + W2 (32KB) + b1 + 16-row T tile (8KB) all in LDS (~104.5 KB).
// 512 threads: phase A = 16 rows x 32 float4 cols; phase B = 16 x 16 (tid<256).
// ===========================================================================
__global__ __launch_bounds__(512) void gemm_fused(const float* __restrict__ aggP,
                                                  const float* __restrict__ W1,
                                                  const float* __restrict__ b1,
                                                  const float* __restrict__ W2,
                                                  float* __restrict__ sup2, int N) {
    __shared__ float4 W1s[128 * 32];  // 64 KB
    __shared__ float4 W2s[128 * 16];  // 32 KB
    __shared__ float4 b1s[32];
    __shared__ float4 Ts[16 * 32];    // 8 KB: relu'd intermediate rows
    for (int i = threadIdx.x; i < 128 * 32; i += 512) W1s[i] = ((const float4*)W1)[i];
    for (int i = threadIdx.x; i < 128 * 16; i += 512) W2s[i] = ((const float4*)W2)[i];
    if (threadIdx.x < 32) b1s[threadIdx.x] = ((const float4*)b1)[threadIdx.x];
    __syncthreads();

    const int r  = threadIdx.x >> 5;  // 0..15
    const int c4 = threadIdx.x & 31;  // 0..31

    for (int row0 = blockIdx.x * 16; row0 < N; row0 += gridDim.x * 16) {
        const int row = row0 + r;
        float4 acc = make_float4(0.f, 0.f, 0.f, 0.f);
        if (row < N) {
            const float4* ar = (const float4*)(aggP + (size_t)row * 128);
#pragma unroll 4
            for (int k4 = 0; k4 < 32; ++k4) {
                const float4 xv = ar[k4];
                const float4 w0 = W1s[(4 * k4 + 0) * 32 + c4];
                const float4 w1 = W1s[(4 * k4 + 1) * 32 + c4];
                const float4 w2 = W1s[(4 * k4 + 2) * 32 + c4];
                const float4 w3 = W1s[(4 * k4 + 3) * 32 + c4];
                acc.x += xv.x * w0.x + xv.y * w1.x + xv.z * w2.x + xv.w * w3.x;
                acc.y += xv.x * w0.y + xv.y * w1.y + xv.z * w2.y + xv.w * w3.y;
                acc.z += xv.x * w0.z + xv.y * w1.z + xv.z * w2.z + xv.w * w3.z;
                acc.w += xv.x * w0.w + xv.y * w1.w + xv.z * w2.w + xv.w * w3.w;
            }
            const float4 bv = b1s[c4];
            acc.x = fmaxf(acc.x + bv.x, 0.f);
            acc.y = fmaxf(acc.y + bv.y, 0.f);
            acc.z = fmaxf(acc.z + bv.z, 0.f);
            acc.w = fmaxf(acc.w + bv.w, 0.f);
        }
        Ts[r * 32 + c4] = acc;  // rows >= N contribute zeros, never read back
        __syncthreads();

        if (threadIdx.x < 256) {
            const int rr = threadIdx.x >> 4;  // 0..15
            const int cc = threadIdx.x & 15;  // 0..15
            const int orow = row0 + rr;
            if (orow < N) {
                float4 a2 = make_float4(0.f, 0.f, 0.f, 0.f);
#pragma unroll 4
                for (int k4 = 0; k4 < 32; ++k4) {
                    const float4 tv = Ts[rr * 32 + k4];
                    const float4 w0 = W2s[(4 * k4 + 0) * 16 + cc];
                    const float4 w1 = W2s[(4 * k4 + 1) * 16 + cc];
                    const float4 w2 = W2s[(4 * k4 + 2) * 16 + cc];
                    const float4 w3 = W2s[(4 * k4 + 3) * 16 + cc];
                    a2.x += tv.x * w0.x + tv.y * w1.x + tv.z * w2.x + tv.w * w3.x;
                    a2.y += tv.x * w0.y + tv.y * w1.y + tv.z * w2.y + tv.w * w3.y;
                    a2.z += tv.x * w0.z + tv.y * w1.z + tv.z * w2.z + tv.w * w3.z;
                    a2.w += tv.x * w0.w + tv.y * w1.w + tv.z * w2.w + tv.w * w3.w;
                }
                ((float4*)(sup2 + (size_t)orow * 64))[cc] = a2;
            }
        }
        __syncthreads();  // Ts reused next iteration
    }
}

extern "C" void kernel_launch(void* const* d_in, const int* in_sizes, int n_in,
                              void* d_out, int out_size, void* d_ws, size_t ws_size,
                              hipStream_t stream) {
    const float* x  = (const float*)d_in[0];
    const int*   ei = (const int*)d_in[1];   // [2, E]: row 0 = dst, row 1 = src
    const float* ew = (const float*)d_in[2];
    const float* W1 = (const float*)d_in[3];
    const float* b1 = (const float*)d_in[4];
    const float* W2 = (const float*)d_in[5];
    const float* b2 = (const float*)d_in[6];
    float* out = (float*)d_out;

    const int* dstIdx = ei;
    const int* srcIdx = ei + N_EDGES;

    // Workspace layout (~90.8 MB total):
    float* aggP    = (float*)d_ws;                         // N*128 f32 = 51.2 MB
    float* sup2    = aggP + (size_t)N_NODES * 128;         // N*64  f32 = 25.6 MB
    int*   csr_src = (int*)(sup2 + (size_t)N_NODES * 64);  // E int     =  6.4 MB
    float* csr_w   = (float*)(csr_src + N_EDGES);          // E f32     =  6.4 MB
    int*   deg     = (int*)(csr_w + N_EDGES);              // N int
    int*   offs    = deg + N_NODES;                        // N+1 int
    int*   cursor  = offs + N_NODES + 1;                   // N int

    const int eblocks = (N_EDGES + 255) / 256;

    // --- CSR build (ws is poisoned 0xAA every call; zero deg first) ---
    hipMemsetAsync(deg, 0, (size_t)N_NODES * sizeof(int), stream);
    count_deg<<<eblocks, 256, 0, stream>>>(dstIdx, deg);
    scan_deg<<<1, 1024, 0, stream>>>(deg, offs, cursor);
    fill_csr<<<eblocks, 256, 0, stream>>>(dstIdx, srcIdx, ew, cursor, csr_src, csr_w);

    // --- Layer 1 aggregate-first: aggP = A @ x (128-wide gather, no bias) ---
    aggregate<128><<<(N_NODES * 64) / 256, 256, 0, stream>>>(x, offs, csr_src, csr_w,
                                                             nullptr, aggP);
    // --- Fused transform: sup2 = relu(aggP@W1 + b1) @ W2 ---
    gemm_fused<<<256, 512, 0, stream>>>(aggP, W1, b1, W2, sup2, N_NODES);

    // --- Layer 2 aggregate (64-wide), bias b2 folded into accumulator init ---
    aggregate<64><<<(N_NODES * 64) / 256, 256, 0, stream>>>(sup2, offs, csr_src, csr_w,
                                                            b2, out);
}

// Round 3
// 607.488 us; speedup vs baseline: 7.0468x; 1.3899x over previous
//
#include <hip/hip_runtime.h>

#define N_NODES 100000
#define N_EDGES 1600000
#define NSB ((N_NODES + 255) / 256)   // 391 scan blocks

// ===========================================================================
// CSR build: histogram -> 3-stage parallel exclusive scan -> fill.
// ===========================================================================
__global__ __launch_bounds__(256) void count_deg(const int* __restrict__ dst,
                                                 int* __restrict__ deg) {
    const int e = blockIdx.x * 256 + threadIdx.x;
    if (e < N_EDGES) atomicAdd(&deg[dst[e]], 1);
}

// Stage A: per-block sums of deg (391 blocks x 256)
__global__ __launch_bounds__(256) void scan_reduce(const int* __restrict__ deg,
                                                   int* __restrict__ bsums) {
    __shared__ int ws[4];
    const int i = blockIdx.x * 256 + threadIdx.x;
    int v = (i < N_NODES) ? deg[i] : 0;
#pragma unroll
    for (int off = 32; off > 0; off >>= 1) v += __shfl_down(v, off, 64);
    if ((threadIdx.x & 63) == 0) ws[threadIdx.x >> 6] = v;
    __syncthreads();
    if (threadIdx.x == 0) bsums[blockIdx.x] = ws[0] + ws[1] + ws[2] + ws[3];
}

// Stage B: single-block exclusive scan of 391 partials (512 threads)
__global__ __launch_bounds__(512) void scan_spine(int* __restrict__ bsums,
                                                  int* __restrict__ offs) {
    __shared__ int s[512];
    const int t = threadIdx.x;
    int v = (t < NSB) ? bsums[t] : 0;
    s[t] = v;
    __syncthreads();
#pragma unroll
    for (int off = 1; off < 512; off <<= 1) {
        int u = (t >= off) ? s[t - off] : 0;
        __syncthreads();
        s[t] += u;
        __syncthreads();
    }
    if (t < NSB) bsums[t] = s[t] - v;       // exclusive
    if (t == 0) offs[N_NODES] = N_EDGES;    // total is a compile-time constant
}

// Stage C: intra-block exclusive scan + apply spine offset -> offs, cursor
__global__ __launch_bounds__(256) void scan_apply(const int* __restrict__ deg,
                                                  const int* __restrict__ bsums,
                                                  int* __restrict__ offs,
                                                  int* __restrict__ cursor) {
    __shared__ int s[256];
    const int t = threadIdx.x;
    const int i = blockIdx.x * 256 + t;
    int v = (i < N_NODES) ? deg[i] : 0;
    s[t] = v;
    __syncthreads();
#pragma unroll
    for (int off = 1; off < 256; off <<= 1) {
        int u = (t >= off) ? s[t - off] : 0;
        __syncthreads();
        s[t] += u;
        __syncthreads();
    }
    if (i < N_NODES) {
        const int o = bsums[blockIdx.x] + s[t] - v;  // exclusive prefix
        offs[i] = o;
        cursor[i] = o;
    }
}

__global__ __launch_bounds__(256) void fill_csr(const int* __restrict__ dst,
                                                const int* __restrict__ src,
                                                const float* __restrict__ ew,
                                                int* __restrict__ cursor,
                                                int* __restrict__ csr_src,
                                                float* __restrict__ csr_w) {
    const int e = blockIdx.x * 256 + threadIdx.x;
    if (e >= N_EDGES) return;
    const int p = atomicAdd(&cursor[dst[e]], 1);
    csr_src[p] = src[e];
    csr_w[p]   = ew[e];
}

// ===========================================================================
// Gather-aggregate: one wave64 per node, 4-edge unroll for MLP.
// ===========================================================================
template <int FEAT>
__global__ __launch_bounds__(256) void aggregate(const float* __restrict__ feat,
                                                 const int* __restrict__ offs,
                                                 const int* __restrict__ csr_src,
                                                 const float* __restrict__ csr_w,
                                                 const float* __restrict__ bias,
                                                 float* __restrict__ out) {
    const int n    = (blockIdx.x * 256 + threadIdx.x) >> 6;
    const int lane = threadIdx.x & 63;
    if (n >= N_NODES) return;
    const int beg = offs[n], end = offs[n + 1];

    if constexpr (FEAT == 128) {
        float2 acc = make_float2(0.f, 0.f);
        int j = beg;
        for (; j + 3 < end; j += 4) {
            const int s0 = csr_src[j], s1 = csr_src[j + 1];
            const int s2 = csr_src[j + 2], s3 = csr_src[j + 3];
            const float w0 = csr_w[j],     w1 = csr_w[j + 1];
            const float w2 = csr_w[j + 2], w3 = csr_w[j + 3];
            const float2 v0 = ((const float2*)(feat + (size_t)s0 * 128))[lane];
            const float2 v1 = ((const float2*)(feat + (size_t)s1 * 128))[lane];
            const float2 v2 = ((const float2*)(feat + (size_t)s2 * 128))[lane];
            const float2 v3 = ((const float2*)(feat + (size_t)s3 * 128))[lane];
            acc.x += w0 * v0.x + w1 * v1.x + w2 * v2.x + w3 * v3.x;
            acc.y += w0 * v0.y + w1 * v1.y + w2 * v2.y + w3 * v3.y;
        }
        for (; j < end; ++j) {
            const float2 v = ((const float2*)(feat + (size_t)csr_src[j] * 128))[lane];
            acc.x += csr_w[j] * v.x;
            acc.y += csr_w[j] * v.y;
        }
        ((float2*)(out + (size_t)n * 128))[lane] = acc;
    } else {
        float acc = bias[lane];
        int j = beg;
        for (; j + 3 < end; j += 4) {
            const int s0 = csr_src[j], s1 = csr_src[j + 1];
            const int s2 = csr_src[j + 2], s3 = csr_src[j + 3];
            const float w0 = csr_w[j],     w1 = csr_w[j + 1];
            const float w2 = csr_w[j + 2], w3 = csr_w[j + 3];
            acc += w0 * feat[(size_t)s0 * 64 + lane] + w1 * feat[(size_t)s1 * 64 + lane]
                 + w2 * feat[(size_t)s2 * 64 + lane] + w3 * feat[(size_t)s3 * 64 + lane];
        }
        for (; j < end; ++j) acc += csr_w[j] * feat[(size_t)csr_src[j] * 64 + lane];
        out[(size_t)n * 64 + lane] = acc;
    }
}

// ===========================================================================
// Fused double GEMM: sup2[N,64] = relu(aggP[N,128] @ W1 + b1) @ W2.
// ===========================================================================
__global__ __launch_bounds__(512) void gemm_fused(const float* __restrict__ aggP,
                                                  const float* __restrict__ W1,
                                                  const float* __restrict__ b1,
                                                  const float* __restrict__ W2,
                                                  float* __restrict__ sup2, int N) {
    __shared__ float4 W1s[128 * 32];  // 64 KB
    __shared__ float4 W2s[128 * 16];  // 32 KB
    __shared__ float4 b1s[32];
    __shared__ float4 Ts[16 * 32];    // 8 KB
    for (int i = threadIdx.x; i < 128 * 32; i += 512) W1s[i] = ((const float4*)W1)[i];
    for (int i = threadIdx.x; i < 128 * 16; i += 512) W2s[i] = ((const float4*)W2)[i];
    if (threadIdx.x < 32) b1s[threadIdx.x] = ((const float4*)b1)[threadIdx.x];
    __syncthreads();

    const int r  = threadIdx.x >> 5;  // 0..15
    const int c4 = threadIdx.x & 31;  // 0..31

    for (int row0 = blockIdx.x * 16; row0 < N; row0 += gridDim.x * 16) {
        const int row = row0 + r;
        float4 acc = make_float4(0.f, 0.f, 0.f, 0.f);
        if (row < N) {
            const float4* ar = (const float4*)(aggP + (size_t)row * 128);
#pragma unroll 4
            for (int k4 = 0; k4 < 32; ++k4) {
                const float4 xv = ar[k4];
                const float4 w0 = W1s[(4 * k4 + 0) * 32 + c4];
                const float4 w1 = W1s[(4 * k4 + 1) * 32 + c4];
                const float4 w2 = W1s[(4 * k4 + 2) * 32 + c4];
                const float4 w3 = W1s[(4 * k4 + 3) * 32 + c4];
                acc.x += xv.x * w0.x + xv.y * w1.x + xv.z * w2.x + xv.w * w3.x;
                acc.y += xv.x * w0.y + xv.y * w1.y + xv.z * w2.y + xv.w * w3.y;
                acc.z += xv.x * w0.z + xv.y * w1.z + xv.z * w2.z + xv.w * w3.z;
                acc.w += xv.x * w0.w + xv.y * w1.w + xv.z * w2.w + xv.w * w3.w;
            }
            const float4 bv = b1s[c4];
            acc.x = fmaxf(acc.x + bv.x, 0.f);
            acc.y = fmaxf(acc.y + bv.y, 0.f);
            acc.z = fmaxf(acc.z + bv.z, 0.f);
            acc.w = fmaxf(acc.w + bv.w, 0.f);
        }
        Ts[r * 32 + c4] = acc;
        __syncthreads();

        if (threadIdx.x < 256) {
            const int rr = threadIdx.x >> 4;
            const int cc = threadIdx.x & 15;
            const int orow = row0 + rr;
            if (orow < N) {
                float4 a2 = make_float4(0.f, 0.f, 0.f, 0.f);
#pragma unroll 4
                for (int k4 = 0; k4 < 32; ++k4) {
                    const float4 tv = Ts[rr * 32 + k4];
                    const float4 w0 = W2s[(4 * k4 + 0) * 16 + cc];
                    const float4 w1 = W2s[(4 * k4 + 1) * 16 + cc];
                    const float4 w2 = W2s[(4 * k4 + 2) * 16 + cc];
                    const float4 w3 = W2s[(4 * k4 + 3) * 16 + cc];
                    a2.x += tv.x * w0.x + tv.y * w1.x + tv.z * w2.x + tv.w * w3.x;
                    a2.y += tv.x * w0.y + tv.y * w1.y + tv.z * w2.y + tv.w * w3.y;
                    a2.z += tv.x * w0.z + tv.y * w1.z + tv.z * w2.z + tv.w * w3.z;
                    a2.w += tv.x * w0.w + tv.y * w1.w + tv.z * w2.w + tv.w * w3.w;
                }
                ((float4*)(sup2 + (size_t)orow * 64))[cc] = a2;
            }
        }
        __syncthreads();
    }
}

extern "C" void kernel_launch(void* const* d_in, const int* in_sizes, int n_in,
                              void* d_out, int out_size, void* d_ws, size_t ws_size,
                              hipStream_t stream) {
    const float* x  = (const float*)d_in[0];
    const int*   ei = (const int*)d_in[1];   // [2, E]: row 0 = dst, row 1 = src
    const float* ew = (const float*)d_in[2];
    const float* W1 = (const float*)d_in[3];
    const float* b1 = (const float*)d_in[4];
    const float* W2 = (const float*)d_in[5];
    const float* b2 = (const float*)d_in[6];
    float* out = (float*)d_out;

    const int* dstIdx = ei;
    const int* srcIdx = ei + N_EDGES;

    // Workspace layout (~91 MB):
    float* aggP    = (float*)d_ws;                         // N*128 f32
    float* sup2    = aggP + (size_t)N_NODES * 128;         // N*64  f32
    int*   csr_src = (int*)(sup2 + (size_t)N_NODES * 64);  // E int
    float* csr_w   = (float*)(csr_src + N_EDGES);          // E f32
    int*   deg     = (int*)(csr_w + N_EDGES);              // N int
    int*   offs    = deg + N_NODES;                        // N+1 int
    int*   cursor  = offs + N_NODES + 1;                   // N int
    int*   bsums   = cursor + N_NODES;                     // NSB int

    const int eblocks = (N_EDGES + 255) / 256;

    // --- CSR build ---
    hipMemsetAsync(deg, 0, (size_t)N_NODES * sizeof(int), stream);
    count_deg<<<eblocks, 256, 0, stream>>>(dstIdx, deg);
    scan_reduce<<<NSB, 256, 0, stream>>>(deg, bsums);
    scan_spine<<<1, 512, 0, stream>>>(bsums, offs);
    scan_apply<<<NSB, 256, 0, stream>>>(deg, bsums, offs, cursor);
    fill_csr<<<eblocks, 256, 0, stream>>>(dstIdx, srcIdx, ew, cursor, csr_src, csr_w);

    // --- Layer 1 aggregate-first: aggP = A @ x ---
    aggregate<128><<<(N_NODES * 64) / 256, 256, 0, stream>>>(x, offs, csr_src, csr_w,
                                                             nullptr, aggP);
    // --- Fused transform: sup2 = relu(aggP@W1 + b1) @ W2 ---
    gemm_fused<<<256, 512, 0, stream>>>(aggP, W1, b1, W2, sup2, N_NODES);

    // --- Layer 2 aggregate, bias b2 folded in ---
    aggregate<64><<<(N_NODES * 64) / 256, 256, 0, stream>>>(sup2, offs, csr_src, csr_w,
                                                            b2, out);
}

// Round 5
// 580.675 us; speedup vs baseline: 7.3722x; 1.0462x over previous
//
#include <hip/hip_runtime.h>

#define N_NODES 100000
#define N_EDGES 1600000
#define NSB ((N_NODES + 255) / 256)   // 391 scan blocks

// ===========================================================================
// CSR build: histogram -> 3-stage parallel exclusive scan -> fill.
// ===========================================================================
__global__ __launch_bounds__(256) void count_deg(const int* __restrict__ dst,
                                                 int* __restrict__ deg) {
    const int e = blockIdx.x * 256 + threadIdx.x;
    if (e < N_EDGES) atomicAdd(&deg[dst[e]], 1);
}

__global__ __launch_bounds__(256) void scan_reduce(const int* __restrict__ deg,
                                                   int* __restrict__ bsums) {
    __shared__ int ws[4];
    const int i = blockIdx.x * 256 + threadIdx.x;
    int v = (i < N_NODES) ? deg[i] : 0;
#pragma unroll
    for (int off = 32; off > 0; off >>= 1) v += __shfl_down(v, off, 64);
    if ((threadIdx.x & 63) == 0) ws[threadIdx.x >> 6] = v;
    __syncthreads();
    if (threadIdx.x == 0) bsums[blockIdx.x] = ws[0] + ws[1] + ws[2] + ws[3];
}

__global__ __launch_bounds__(512) void scan_spine(int* __restrict__ bsums,
                                                  int* __restrict__ offs) {
    __shared__ int s[512];
    const int t = threadIdx.x;
    int v = (t < NSB) ? bsums[t] : 0;
    s[t] = v;
    __syncthreads();
#pragma unroll
    for (int off = 1; off < 512; off <<= 1) {
        int u = (t >= off) ? s[t - off] : 0;
        __syncthreads();
        s[t] += u;
        __syncthreads();
    }
    if (t < NSB) bsums[t] = s[t] - v;       // exclusive
    if (t == 0) offs[N_NODES] = N_EDGES;
}

__global__ __launch_bounds__(256) void scan_apply(const int* __restrict__ deg,
                                                  const int* __restrict__ bsums,
                                                  int* __restrict__ offs,
                                                  int* __restrict__ cursor) {
    __shared__ int s[256];
    const int t = threadIdx.x;
    const int i = blockIdx.x * 256 + t;
    int v = (i < N_NODES) ? deg[i] : 0;
    s[t] = v;
    __syncthreads();
#pragma unroll
    for (int off = 1; off < 256; off <<= 1) {
        int u = (t >= off) ? s[t - off] : 0;
        __syncthreads();
        s[t] += u;
        __syncthreads();
    }
    if (i < N_NODES) {
        const int o = bsums[blockIdx.x] + s[t] - v;
        offs[i] = o;
        cursor[i] = o;
    }
}

__global__ __launch_bounds__(256) void fill_csr(const int* __restrict__ dst,
                                                const int* __restrict__ src,
                                                const float* __restrict__ ew,
                                                int* __restrict__ cursor,
                                                int* __restrict__ csr_src,
                                                float* __restrict__ csr_w) {
    const int e = blockIdx.x * 256 + threadIdx.x;
    if (e >= N_EDGES) return;
    const int p = atomicAdd(&cursor[dst[e]], 1);
    csr_src[p] = src[e];
    csr_w[p]   = ew[e];
}

// ===========================================================================
// Gather-aggregate: one wave64 per node, 4-edge unroll for MLP.
// ===========================================================================
template <int FEAT>
__global__ __launch_bounds__(256) void aggregate(const float* __restrict__ feat,
                                                 const int* __restrict__ offs,
                                                 const int* __restrict__ csr_src,
                                                 const float* __restrict__ csr_w,
                                                 const float* __restrict__ bias,
                                                 float* __restrict__ out) {
    const int n    = (blockIdx.x * 256 + threadIdx.x) >> 6;
    const int lane = threadIdx.x & 63;
    if (n >= N_NODES) return;
    const int beg = offs[n], end = offs[n + 1];

    if constexpr (FEAT == 128) {
        float2 acc = make_float2(0.f, 0.f);
        int j = beg;
        for (; j + 3 < end; j += 4) {
            const int s0 = csr_src[j], s1 = csr_src[j + 1];
            const int s2 = csr_src[j + 2], s3 = csr_src[j + 3];
            const float w0 = csr_w[j],     w1 = csr_w[j + 1];
            const float w2 = csr_w[j + 2], w3 = csr_w[j + 3];
            const float2 v0 = ((const float2*)(feat + (size_t)s0 * 128))[lane];
            const float2 v1 = ((const float2*)(feat + (size_t)s1 * 128))[lane];
            const float2 v2 = ((const float2*)(feat + (size_t)s2 * 128))[lane];
            const float2 v3 = ((const float2*)(feat + (size_t)s3 * 128))[lane];
            acc.x += w0 * v0.x + w1 * v1.x + w2 * v2.x + w3 * v3.x;
            acc.y += w0 * v0.y + w1 * v1.y + w2 * v2.y + w3 * v3.y;
        }
        for (; j < end; ++j) {
            const float2 v = ((const float2*)(feat + (size_t)csr_src[j] * 128))[lane];
            acc.x += csr_w[j] * v.x;
            acc.y += csr_w[j] * v.y;
        }
        ((float2*)(out + (size_t)n * 128))[lane] = acc;
    } else {
        float acc = bias[lane];
        int j = beg;
        for (; j + 3 < end; j += 4) {
            const int s0 = csr_src[j], s1 = csr_src[j + 1];
            const int s2 = csr_src[j + 2], s3 = csr_src[j + 3];
            const float w0 = csr_w[j],     w1 = csr_w[j + 1];
            const float w2 = csr_w[j + 2], w3 = csr_w[j + 3];
            acc += w0 * feat[(size_t)s0 * 64 + lane] + w1 * feat[(size_t)s1 * 64 + lane]
                 + w2 * feat[(size_t)s2 * 64 + lane] + w3 * feat[(size_t)s3 * 64 + lane];
        }
        for (; j < end; ++j) acc += csr_w[j] * feat[(size_t)csr_src[j] * 64 + lane];
        out[(size_t)n * 64 + lane] = acc;
    }
}

// ===========================================================================
// Fused double GEMM, register-blocked:
//   sup2[N,64] = relu(aggP[N,128] @ W1 + b1) @ W2
// 256 threads; 128-row tile; A staged TRANSPOSED in LDS (AT[k][row]).
// Phase A: 8x8 outer product/thread (64 FMA per 4 b128 LDS reads).
// T^t written back into the A buffer; Phase B: 8x4 outer product.
// LDS: W1 64K + W2 32K + AT 64K = exactly 160 KiB -> 1 block/CU, 4 waves.
// ===========================================================================
__device__ __forceinline__ void fma4(float4& a, float s, const float4& v) {
    a.x += s * v.x; a.y += s * v.y; a.z += s * v.z; a.w += s * v.w;
}

__global__ __launch_bounds__(256) void gemm_fused(const float* __restrict__ aggP,
                                                  const float* __restrict__ W1,
                                                  const float* __restrict__ b1,
                                                  const float* __restrict__ W2,
                                                  float* __restrict__ sup2, int N) {
    __shared__ __align__(16) float W1s[128 * 128];  // 64 KB  [k][col]
    __shared__ __align__(16) float W2s[128 * 64];   // 32 KB  [k][col]
    __shared__ __align__(16) float AT[128 * 128];   // 64 KB  [k][row], reused as T^t
    float4* W14 = (float4*)W1s;
    float4* W24 = (float4*)W2s;
    float4* AT4 = (float4*)AT;

    for (int i = threadIdx.x; i < 128 * 32; i += 256) W14[i] = ((const float4*)W1)[i];
    for (int i = threadIdx.x; i < 128 * 16; i += 256) W24[i] = ((const float4*)W2)[i];

    const int rg = threadIdx.x & 15;   // phase A: row group (8 rows)
    const int cg = threadIdx.x >> 4;   // phase A: col group (8 cols)
    // b1 fragment in registers (cols cg*8..cg*8+7)
    const float4 b1a = ((const float4*)b1)[cg * 2];
    const float4 b1b = ((const float4*)b1)[cg * 2 + 1];

    for (int tile = blockIdx.x; tile * 128 < N; tile += gridDim.x) {
        const int row0 = tile * 128;
        __syncthreads();  // previous iteration's phase-B reads of AT done

        // ---- Stage A transposed: AT[k][row] (lane-row-consecutive writes) --
#pragma unroll
        for (int i = 0; i < 16; ++i) {
            const int idx  = i * 256 + threadIdx.x;
            const int row  = idx & 127;
            const int k4   = idx >> 7;          // 0..31
            const int grow = row0 + row;
            float4 v = make_float4(0.f, 0.f, 0.f, 0.f);
            if (grow < N) v = ((const float4*)aggP)[(size_t)grow * 32 + k4];
            AT[(k4 * 4 + 0) * 128 + row] = v.x;
            AT[(k4 * 4 + 1) * 128 + row] = v.y;
            AT[(k4 * 4 + 2) * 128 + row] = v.z;
            AT[(k4 * 4 + 3) * 128 + row] = v.w;
        }
        __syncthreads();

        // ---- Phase A: T = relu(A@W1 + b1), 8x8 per thread ------------------
        float4 acc[8][2];
#pragma unroll
        for (int i = 0; i < 8; ++i) {
            acc[i][0] = make_float4(0.f, 0.f, 0.f, 0.f);
            acc[i][1] = make_float4(0.f, 0.f, 0.f, 0.f);
        }
        float4 a0 = AT4[rg * 2],     a1 = AT4[rg * 2 + 1];
        float4 w0 = W14[cg * 2],     w1 = W14[cg * 2 + 1];
        for (int k = 0; k < 128; ++k) {
            const int kn = (k + 1) & 127;
            const float4 na0 = AT4[kn * 32 + rg * 2];
            const float4 na1 = AT4[kn * 32 + rg * 2 + 1];
            const float4 nw0 = W14[kn * 32 + cg * 2];
            const float4 nw1 = W14[kn * 32 + cg * 2 + 1];
            const float a[8] = {a0.x, a0.y, a0.z, a0.w, a1.x, a1.y, a1.z, a1.w};
#pragma unroll
            for (int i = 0; i < 8; ++i) {
                fma4(acc[i][0], a[i], w0);
                fma4(acc[i][1], a[i], w1);
            }
            a0 = na0; a1 = na1; w0 = nw0; w1 = nw1;
        }
        // bias + relu
#pragma unroll
        for (int i = 0; i < 8; ++i) {
            acc[i][0].x = fmaxf(acc[i][0].x + b1a.x, 0.f);
            acc[i][0].y = fmaxf(acc[i][0].y + b1a.y, 0.f);
            acc[i][0].z = fmaxf(acc[i][0].z + b1a.z, 0.f);
            acc[i][0].w = fmaxf(acc[i][0].w + b1a.w, 0.f);
            acc[i][1].x = fmaxf(acc[i][1].x + b1b.x, 0.f);
            acc[i][1].y = fmaxf(acc[i][1].y + b1b.y, 0.f);
            acc[i][1].z = fmaxf(acc[i][1].z + b1b.z, 0.f);
            acc[i][1].w = fmaxf(acc[i][1].w + b1b.w, 0.f);
        }
        __syncthreads();  // all phase-A reads of AT done before overwrite

        // ---- Write T^t into AT: AT[c][r], c = cg*8+j, r = rg*8..+7 ---------
#pragma unroll
        for (int j = 0; j < 8; ++j) {
            const float* p0 = (const float*)&acc[0][j >> 2];
            const float* p1 = (const float*)&acc[1][j >> 2];
            const float* p2 = (const float*)&acc[2][j >> 2];
            const float* p3 = (const float*)&acc[3][j >> 2];
            const float* p4 = (const float*)&acc[4][j >> 2];
            const float* p5 = (const float*)&acc[5][j >> 2];
            const float* p6 = (const float*)&acc[6][j >> 2];
            const float* p7 = (const float*)&acc[7][j >> 2];
            const int jc = j & 3;
            const float4 lo = make_float4(p0[jc], p1[jc], p2[jc], p3[jc]);
            const float4 hi = make_float4(p4[jc], p5[jc], p6[jc], p7[jc]);
            AT4[(cg * 8 + j) * 32 + rg * 2]     = lo;
            AT4[(cg * 8 + j) * 32 + rg * 2 + 1] = hi;
        }
        __syncthreads();

        // ---- Phase B: out = T @ W2, 8x4 per thread -------------------------
        const int rg2 = threadIdx.x & 15;  // 8 rows
        const int cg2 = threadIdx.x >> 4;  // 4 cols
        float4 acc2[8];
#pragma unroll
        for (int i = 0; i < 8; ++i) acc2[i] = make_float4(0.f, 0.f, 0.f, 0.f);
        float4 t0 = AT4[rg2 * 2], t1 = AT4[rg2 * 2 + 1];
        float4 wv = W24[cg2];
        for (int k = 0; k < 128; ++k) {
            const int kn = (k + 1) & 127;
            const float4 nt0 = AT4[kn * 32 + rg2 * 2];
            const float4 nt1 = AT4[kn * 32 + rg2 * 2 + 1];
            const float4 nwv = W24[kn * 16 + cg2];
            const float tv[8] = {t0.x, t0.y, t0.z, t0.w, t1.x, t1.y, t1.z, t1.w};
#pragma unroll
            for (int i = 0; i < 8; ++i) { fma4(acc2[i], tv[i], wv); }
            t0 = nt0; t1 = nt1; wv = nwv;
        }
#pragma unroll
        for (int i = 0; i < 8; ++i) {
            const int row = row0 + rg2 * 8 + i;
            if (row < N) ((float4*)sup2)[(size_t)row * 16 + cg2] = acc2[i];
        }
    }
}

extern "C" void kernel_launch(void* const* d_in, const int* in_sizes, int n_in,
                              void* d_out, int out_size, void* d_ws, size_t ws_size,
                              hipStream_t stream) {
    const float* x  = (const float*)d_in[0];
    const int*   ei = (const int*)d_in[1];   // [2, E]: row 0 = dst, row 1 = src
    const float* ew = (const float*)d_in[2];
    const float* W1 = (const float*)d_in[3];
    const float* b1 = (const float*)d_in[4];
    const float* W2 = (const float*)d_in[5];
    const float* b2 = (const float*)d_in[6];
    float* out = (float*)d_out;

    const int* dstIdx = ei;
    const int* srcIdx = ei + N_EDGES;

    // Workspace layout (~91 MB):
    float* aggP    = (float*)d_ws;                         // N*128 f32
    float* sup2    = aggP + (size_t)N_NODES * 128;         // N*64  f32
    int*   csr_src = (int*)(sup2 + (size_t)N_NODES * 64);  // E int
    float* csr_w   = (float*)(csr_src + N_EDGES);          // E f32
    int*   deg     = (int*)(csr_w + N_EDGES);              // N int
    int*   offs    = deg + N_NODES;                        // N+1 int
    int*   cursor  = offs + N_NODES + 1;                   // N int
    int*   bsums   = cursor + N_NODES;                     // NSB int

    const int eblocks = (N_EDGES + 255) / 256;

    // --- CSR build ---
    (void)hipMemsetAsync(deg, 0, (size_t)N_NODES * sizeof(int), stream);
    count_deg<<<eblocks, 256, 0, stream>>>(dstIdx, deg);
    scan_reduce<<<NSB, 256, 0, stream>>>(deg, bsums);
    scan_spine<<<1, 512, 0, stream>>>(bsums, offs);
    scan_apply<<<NSB, 256, 0, stream>>>(deg, bsums, offs, cursor);
    fill_csr<<<eblocks, 256, 0, stream>>>(dstIdx, srcIdx, ew, cursor, csr_src, csr_w);

    // --- Layer 1 aggregate-first: aggP = A @ x ---
    aggregate<128><<<(N_NODES * 64) / 256, 256, 0, stream>>>(x, offs, csr_src, csr_w,
                                                             nullptr, aggP);
    // --- Fused transform: sup2 = relu(aggP@W1 + b1) @ W2 ---
    gemm_fused<<<256, 256, 0, stream>>>(aggP, W1, b1, W2, sup2, N_NODES);

    // --- Layer 2 aggregate, bias b2 folded in ---
    aggregate<64><<<(N_NODES * 64) / 256, 256, 0, stream>>>(sup2, offs, csr_src, csr_w,
                                                            b2, out);
}

// Round 6
// 543.983 us; speedup vs baseline: 7.8694x; 1.0675x over previous
//
#include <hip/hip_runtime.h>

#define N_NODES 100000
#define N_EDGES 1600000
#define NSB ((N_NODES + 255) / 256)   // 391 scan blocks

typedef unsigned int uint32;

// bf16 round-to-nearest-even helpers
__device__ __forceinline__ uint32 bf16_rne(float f) {
    uint32 u = __float_as_uint(f);
    return (u + 0x7fffu + ((u >> 16) & 1u)) >> 16;
}
__device__ __forceinline__ uint32 pack_bf16x2(float lo, float hi) {
    return bf16_rne(lo) | (bf16_rne(hi) << 16);
}
__device__ __forceinline__ float bf16_lo(uint32 u) { return __uint_as_float(u << 16); }
__device__ __forceinline__ float bf16_hi(uint32 u) { return __uint_as_float(u & 0xFFFF0000u); }

// ===========================================================================
// x [N,128] f32 -> packed bf16 (one uint32 = 2 features)
// ===========================================================================
__global__ __launch_bounds__(256) void conv_x(const float* __restrict__ x,
                                              uint32* __restrict__ xb) {
    const int t = blockIdx.x * 256 + threadIdx.x;   // over N*64
    if (t >= N_NODES * 64) return;
    const float2 v = ((const float2*)x)[t];
    xb[t] = pack_bf16x2(v.x, v.y);
}

// ===========================================================================
// CSR build: histogram -> 3-stage parallel exclusive scan -> fill (int2 pairs).
// ===========================================================================
__global__ __launch_bounds__(256) void count_deg(const int* __restrict__ dst,
                                                 int* __restrict__ deg) {
    const int e = blockIdx.x * 256 + threadIdx.x;
    if (e < N_EDGES) atomicAdd(&deg[dst[e]], 1);
}

__global__ __launch_bounds__(256) void scan_reduce(const int* __restrict__ deg,
                                                   int* __restrict__ bsums) {
    __shared__ int ws[4];
    const int i = blockIdx.x * 256 + threadIdx.x;
    int v = (i < N_NODES) ? deg[i] : 0;
#pragma unroll
    for (int off = 32; off > 0; off >>= 1) v += __shfl_down(v, off, 64);
    if ((threadIdx.x & 63) == 0) ws[threadIdx.x >> 6] = v;
    __syncthreads();
    if (threadIdx.x == 0) bsums[blockIdx.x] = ws[0] + ws[1] + ws[2] + ws[3];
}

__global__ __launch_bounds__(512) void scan_spine(int* __restrict__ bsums,
                                                  int* __restrict__ offs) {
    __shared__ int s[512];
    const int t = threadIdx.x;
    int v = (t < NSB) ? bsums[t] : 0;
    s[t] = v;
    __syncthreads();
#pragma unroll
    for (int off = 1; off < 512; off <<= 1) {
        int u = (t >= off) ? s[t - off] : 0;
        __syncthreads();
        s[t] += u;
        __syncthreads();
    }
    if (t < NSB) bsums[t] = s[t] - v;       // exclusive
    if (t == 0) offs[N_NODES] = N_EDGES;
}

__global__ __launch_bounds__(256) void scan_apply(const int* __restrict__ deg,
                                                  const int* __restrict__ bsums,
                                                  int* __restrict__ offs,
                                                  int* __restrict__ cursor) {
    __shared__ int s[256];
    const int t = threadIdx.x;
    const int i = blockIdx.x * 256 + t;
    int v = (i < N_NODES) ? deg[i] : 0;
    s[t] = v;
    __syncthreads();
#pragma unroll
    for (int off = 1; off < 256; off <<= 1) {
        int u = (t >= off) ? s[t - off] : 0;
        __syncthreads();
        s[t] += u;
        __syncthreads();
    }
    if (i < N_NODES) {
        const int o = bsums[blockIdx.x] + s[t] - v;
        offs[i] = o;
        cursor[i] = o;
    }
}

__global__ __launch_bounds__(256) void fill_csr(const int* __restrict__ dst,
                                                const int* __restrict__ src,
                                                const float* __restrict__ ew,
                                                int* __restrict__ cursor,
                                                int2* __restrict__ csr_ef) {
    const int e = blockIdx.x * 256 + threadIdx.x;
    if (e >= N_EDGES) return;
    const int p = atomicAdd(&cursor[dst[e]], 1);
    csr_ef[p] = make_int2(src[e], __float_as_int(ew[e]));
}

// ===========================================================================
// Gather-aggregate over bf16 feature tables, fp32 accumulate.
// FEAT=128: lane reads uint32 (2 feats, 256 B/row). FEAT=64: lane reads
// ushort (1 feat, 128 B/row). One wave64 per node, 4-edge unroll.
// ===========================================================================
template <int FEAT>
__global__ __launch_bounds__(256) void aggregate(const void* __restrict__ featv,
                                                 const int* __restrict__ offs,
                                                 const int2* __restrict__ csr_ef,
                                                 const float* __restrict__ bias,
                                                 float* __restrict__ out) {
    const int n    = (blockIdx.x * 256 + threadIdx.x) >> 6;
    const int lane = threadIdx.x & 63;
    if (n >= N_NODES) return;
    const int beg = offs[n], end = offs[n + 1];

    if constexpr (FEAT == 128) {
        const uint32* feat = (const uint32*)featv;
        float2 acc = make_float2(0.f, 0.f);
        int j = beg;
        for (; j + 3 < end; j += 4) {
            const int2 e0 = csr_ef[j],     e1 = csr_ef[j + 1];
            const int2 e2 = csr_ef[j + 2], e3 = csr_ef[j + 3];
            const uint32 v0 = feat[(size_t)e0.x * 64 + lane];
            const uint32 v1 = feat[(size_t)e1.x * 64 + lane];
            const uint32 v2 = feat[(size_t)e2.x * 64 + lane];
            const uint32 v3 = feat[(size_t)e3.x * 64 + lane];
            const float w0 = __int_as_float(e0.y), w1 = __int_as_float(e1.y);
            const float w2 = __int_as_float(e2.y), w3 = __int_as_float(e3.y);
            acc.x += w0 * bf16_lo(v0) + w1 * bf16_lo(v1) + w2 * bf16_lo(v2) + w3 * bf16_lo(v3);
            acc.y += w0 * bf16_hi(v0) + w1 * bf16_hi(v1) + w2 * bf16_hi(v2) + w3 * bf16_hi(v3);
        }
        for (; j < end; ++j) {
            const int2 e0 = csr_ef[j];
            const uint32 v = feat[(size_t)e0.x * 64 + lane];
            const float w = __int_as_float(e0.y);
            acc.x += w * bf16_lo(v);
            acc.y += w * bf16_hi(v);
        }
        ((float2*)(out + (size_t)n * 128))[lane] = acc;
    } else {
        const unsigned short* feat = (const unsigned short*)featv;
        float acc = bias[lane];
        int j = beg;
        for (; j + 3 < end; j += 4) {
            const int2 e0 = csr_ef[j],     e1 = csr_ef[j + 1];
            const int2 e2 = csr_ef[j + 2], e3 = csr_ef[j + 3];
            const float f0 = __uint_as_float((uint32)feat[(size_t)e0.x * 64 + lane] << 16);
            const float f1 = __uint_as_float((uint32)feat[(size_t)e1.x * 64 + lane] << 16);
            const float f2 = __uint_as_float((uint32)feat[(size_t)e2.x * 64 + lane] << 16);
            const float f3 = __uint_as_float((uint32)feat[(size_t)e3.x * 64 + lane] << 16);
            acc += __int_as_float(e0.y) * f0 + __int_as_float(e1.y) * f1
                 + __int_as_float(e2.y) * f2 + __int_as_float(e3.y) * f3;
        }
        for (; j < end; ++j) {
            const int2 e0 = csr_ef[j];
            acc += __int_as_float(e0.y)
                 * __uint_as_float((uint32)feat[(size_t)e0.x * 64 + lane] << 16);
        }
        out[(size_t)n * 64 + lane] = acc;
    }
}

// ===========================================================================
// Fused double GEMM, register-blocked (fp32 math, bf16 output):
//   sup2b[N,64](bf16) = relu(aggP[N,128] @ W1 + b1) @ W2
// ===========================================================================
__device__ __forceinline__ void fma4(float4& a, float s, const float4& v) {
    a.x += s * v.x; a.y += s * v.y; a.z += s * v.z; a.w += s * v.w;
}

__global__ __launch_bounds__(256) void gemm_fused(const float* __restrict__ aggP,
                                                  const float* __restrict__ W1,
                                                  const float* __restrict__ b1,
                                                  const float* __restrict__ W2,
                                                  uint32* __restrict__ sup2b, int N) {
    __shared__ __align__(16) float W1s[128 * 128];  // 64 KB  [k][col]
    __shared__ __align__(16) float W2s[128 * 64];   // 32 KB  [k][col]
    __shared__ __align__(16) float AT[128 * 128];   // 64 KB  [k][row], reused as T^t
    float4* W14 = (float4*)W1s;
    float4* W24 = (float4*)W2s;
    float4* AT4 = (float4*)AT;

    for (int i = threadIdx.x; i < 128 * 32; i += 256) W14[i] = ((const float4*)W1)[i];
    for (int i = threadIdx.x; i < 128 * 16; i += 256) W24[i] = ((const float4*)W2)[i];

    const int rg = threadIdx.x & 15;   // phase A: row group (8 rows)
    const int cg = threadIdx.x >> 4;   // phase A: col group (8 cols)
    const float4 b1a = ((const float4*)b1)[cg * 2];
    const float4 b1b = ((const float4*)b1)[cg * 2 + 1];

    for (int tile = blockIdx.x; tile * 128 < N; tile += gridDim.x) {
        const int row0 = tile * 128;
        __syncthreads();  // previous iteration's phase-B reads of AT done

        // ---- Stage A transposed: AT[k][row] --------------------------------
#pragma unroll
        for (int i = 0; i < 16; ++i) {
            const int idx  = i * 256 + threadIdx.x;
            const int row  = idx & 127;
            const int k4   = idx >> 7;          // 0..31
            const int grow = row0 + row;
            float4 v = make_float4(0.f, 0.f, 0.f, 0.f);
            if (grow < N) v = ((const float4*)aggP)[(size_t)grow * 32 + k4];
            AT[(k4 * 4 + 0) * 128 + row] = v.x;
            AT[(k4 * 4 + 1) * 128 + row] = v.y;
            AT[(k4 * 4 + 2) * 128 + row] = v.z;
            AT[(k4 * 4 + 3) * 128 + row] = v.w;
        }
        __syncthreads();

        // ---- Phase A: T = relu(A@W1 + b1), 8x8 per thread ------------------
        float4 acc[8][2];
#pragma unroll
        for (int i = 0; i < 8; ++i) {
            acc[i][0] = make_float4(0.f, 0.f, 0.f, 0.f);
            acc[i][1] = make_float4(0.f, 0.f, 0.f, 0.f);
        }
        float4 a0 = AT4[rg * 2],     a1 = AT4[rg * 2 + 1];
        float4 w0 = W14[cg * 2],     w1 = W14[cg * 2 + 1];
        for (int k = 0; k < 128; ++k) {
            const int kn = (k + 1) & 127;
            const float4 na0 = AT4[kn * 32 + rg * 2];
            const float4 na1 = AT4[kn * 32 + rg * 2 + 1];
            const float4 nw0 = W14[kn * 32 + cg * 2];
            const float4 nw1 = W14[kn * 32 + cg * 2 + 1];
            const float a[8] = {a0.x, a0.y, a0.z, a0.w, a1.x, a1.y, a1.z, a1.w};
#pragma unroll
            for (int i = 0; i < 8; ++i) {
                fma4(acc[i][0], a[i], w0);
                fma4(acc[i][1], a[i], w1);
            }
            a0 = na0; a1 = na1; w0 = nw0; w1 = nw1;
        }
#pragma unroll
        for (int i = 0; i < 8; ++i) {
            acc[i][0].x = fmaxf(acc[i][0].x + b1a.x, 0.f);
            acc[i][0].y = fmaxf(acc[i][0].y + b1a.y, 0.f);
            acc[i][0].z = fmaxf(acc[i][0].z + b1a.z, 0.f);
            acc[i][0].w = fmaxf(acc[i][0].w + b1a.w, 0.f);
            acc[i][1].x = fmaxf(acc[i][1].x + b1b.x, 0.f);
            acc[i][1].y = fmaxf(acc[i][1].y + b1b.y, 0.f);
            acc[i][1].z = fmaxf(acc[i][1].z + b1b.z, 0.f);
            acc[i][1].w = fmaxf(acc[i][1].w + b1b.w, 0.f);
        }
        __syncthreads();  // all phase-A reads of AT done before overwrite

        // ---- Write T^t into AT: AT[c][r] -----------------------------------
#pragma unroll
        for (int j = 0; j < 8; ++j) {
            const float* p0 = (const float*)&acc[0][j >> 2];
            const float* p1 = (const float*)&acc[1][j >> 2];
            const float* p2 = (const float*)&acc[2][j >> 2];
            const float* p3 = (const float*)&acc[3][j >> 2];
            const float* p4 = (const float*)&acc[4][j >> 2];
            const float* p5 = (const float*)&acc[5][j >> 2];
            const float* p6 = (const float*)&acc[6][j >> 2];
            const float* p7 = (const float*)&acc[7][j >> 2];
            const int jc = j & 3;
            const float4 lo = make_float4(p0[jc], p1[jc], p2[jc], p3[jc]);
            const float4 hi = make_float4(p4[jc], p5[jc], p6[jc], p7[jc]);
            AT4[(cg * 8 + j) * 32 + rg * 2]     = lo;
            AT4[(cg * 8 + j) * 32 + rg * 2 + 1] = hi;
        }
        __syncthreads();

        // ---- Phase B: out = T @ W2, 8 rows x 4 feats per thread, bf16 out --
        const int rg2 = threadIdx.x & 15;  // 8-row group
        const int cg2 = threadIdx.x >> 4;  // 0..15 -> feats 4*cg2..+3
        float4 acc2[8];
#pragma unroll
        for (int i = 0; i < 8; ++i) acc2[i] = make_float4(0.f, 0.f, 0.f, 0.f);
        float4 t0 = AT4[rg2 * 2], t1 = AT4[rg2 * 2 + 1];
        float4 wv = W24[cg2];
        for (int k = 0; k < 128; ++k) {
            const int kn = (k + 1) & 127;
            const float4 nt0 = AT4[kn * 32 + rg2 * 2];
            const float4 nt1 = AT4[kn * 32 + rg2 * 2 + 1];
            const float4 nwv = W24[kn * 16 + cg2];
            const float tv[8] = {t0.x, t0.y, t0.z, t0.w, t1.x, t1.y, t1.z, t1.w};
#pragma unroll
            for (int i = 0; i < 8; ++i) { fma4(acc2[i], tv[i], wv); }
            t0 = nt0; t1 = nt1; wv = nwv;
        }
#pragma unroll
        for (int i = 0; i < 8; ++i) {
            const int row = row0 + rg2 * 8 + i;
            if (row < N) {
                uint2 pk;
                pk.x = pack_bf16x2(acc2[i].x, acc2[i].y);
                pk.y = pack_bf16x2(acc2[i].z, acc2[i].w);
                ((uint2*)sup2b)[(size_t)row * 16 + cg2] = pk;
            }
        }
    }
}

extern "C" void kernel_launch(void* const* d_in, const int* in_sizes, int n_in,
                              void* d_out, int out_size, void* d_ws, size_t ws_size,
                              hipStream_t stream) {
    const float* x  = (const float*)d_in[0];
    const int*   ei = (const int*)d_in[1];   // [2, E]: row 0 = dst, row 1 = src
    const float* ew = (const float*)d_in[2];
    const float* W1 = (const float*)d_in[3];
    const float* b1 = (const float*)d_in[4];
    const float* W2 = (const float*)d_in[5];
    const float* b2 = (const float*)d_in[6];
    float* out = (float*)d_out;

    const int* dstIdx = ei;
    const int* srcIdx = ei + N_EDGES;

    // Workspace layout (~90.8 MB, same footprint as round 5):
    //   region A (25.6 MB): x_bf16 [N*64 uint]; later aliased by sup2_bf16
    //     [N*16 uint2 = 12.8 MB] — x_bf16 is dead once aggregate<128> is done.
    uint32* xb      = (uint32*)d_ws;                       // N*64 uint  = 25.6 MB
    float*  aggP    = (float*)(xb + (size_t)N_NODES * 64); // N*128 f32  = 51.2 MB
    int2*   csr_ef  = (int2*)(aggP + (size_t)N_NODES * 128); // E int2   = 12.8 MB
    int*    deg     = (int*)(csr_ef + N_EDGES);            // N int
    int*    offs    = deg + N_NODES;                       // N+1 int
    int*    cursor  = offs + N_NODES + 1;                  // N int
    int*    bsums   = cursor + N_NODES;                    // NSB int
    uint32* sup2b   = xb;                                  // alias (see above)

    const int eblocks = (N_EDGES + 255) / 256;

    // --- x -> bf16 + CSR build ---
    (void)hipMemsetAsync(deg, 0, (size_t)N_NODES * sizeof(int), stream);
    conv_x<<<(N_NODES * 64 + 255) / 256, 256, 0, stream>>>(x, xb);
    count_deg<<<eblocks, 256, 0, stream>>>(dstIdx, deg);
    scan_reduce<<<NSB, 256, 0, stream>>>(deg, bsums);
    scan_spine<<<1, 512, 0, stream>>>(bsums, offs);
    scan_apply<<<NSB, 256, 0, stream>>>(deg, bsums, offs, cursor);
    fill_csr<<<eblocks, 256, 0, stream>>>(dstIdx, srcIdx, ew, cursor, csr_ef);

    // --- Layer 1 aggregate-first: aggP = A @ x  (bf16 gather, fp32 acc) ---
    aggregate<128><<<(N_NODES * 64) / 256, 256, 0, stream>>>(xb, offs, csr_ef,
                                                             nullptr, aggP);
    // --- Fused transform: sup2b = bf16(relu(aggP@W1 + b1) @ W2) ---
    gemm_fused<<<256, 256, 0, stream>>>(aggP, W1, b1, W2, sup2b, N_NODES);

    // --- Layer 2 aggregate (bf16 gather), bias b2 folded in ---
    aggregate<64><<<(N_NODES * 64) / 256, 256, 0, stream>>>(sup2b, offs, csr_ef,
                                                            b2, out);
}